// Round 1
// baseline (306.725 us; speedup 1.0000x reference)
//
#include <hip/hip_runtime.h>

// PrimalCosAttention fused kernel (fp32, VALU GEMMs).
// B=4 H=12 N=4096 D=64 E=32. One block = one (b,h) x 64-row n-tile.
// Outputs concatenated: attn, escore, rscore, we0, wr0, queries, keys, Lambda.

namespace {
constexpr int Hh = 12;
constexpr int Nn = 4096;
constexpr int Dd = 64;
// output offsets in floats
constexpr int O_ATTN = 0;
constexpr int O_ES   = 12582912;
constexpr int O_RS   = 18874368;
constexpr int O_WE   = 25165824;
constexpr int O_WR   = 25190400;
constexpr int O_Q    = 25214976;
constexpr int O_K    = 37797888;
constexpr int O_LAM  = 50380800;
}

// A-region swizzle: A is [d=64][128] (cols 0..63 = qn rows, 64..127 = kn rows).
// XOR swizzle on row index breaks the stride-128 (bank-aligned) conflict for
// the [d][n] transpose writes while keeping 4-row groups contiguous+16B-aligned
// for float4 reads. Reads use the identical formula.
__device__ __forceinline__ int aswz(int d, int r) {
    return d * 128 + (r ^ ((d & 7) << 2));
}

__global__ __launch_bounds__(256, 2)
void pca_fused(const float* __restrict__ Q, const float* __restrict__ Kp,
               const float* __restrict__ we, const float* __restrict__ wr,
               const float* __restrict__ mask, const float* __restrict__ W,
               const float* __restrict__ bias, float* __restrict__ out)
{
    __shared__ float lds[16384];          // exactly 64 KiB -> 2 blocks/CU
    float* A  = lds;                      // [64][128] swizzled qn|kn; reused as St
    float* Bs = lds + 8192;               // [k=d 64][64]  we_h | wr_h
    float* Ws = lds + 12288;              // [k=e 64][64]  W^T, swizzled

    const int tid = threadIdx.x;
    const int bh  = blockIdx.x >> 6;      // 0..47  (b*12+h)
    const int n0  = (blockIdx.x & 63) << 6;
    const int h   = bh % Hh;
    const int bb  = bh / Hh;

    // ---- stage Bs = [we_h | wr_h]  (row = d, col = e2) ----
    {
        const float* weh = we + h * 2048;   // we[0][h][.][.]
        const float* wrh = wr + h * 2048;
#pragma unroll
        for (int j = 0; j < 8; ++j) {
            int i = tid + 256 * j;          // 0..2047
            int d = i >> 5, e = i & 31;
            Bs[d * 64 + e]      = weh[i];
            Bs[d * 64 + 32 + e] = wrh[i];
        }
    }
    // ---- stage Ws[e][d] = W[d][e]  (transposed, d-swizzled) ----
    {
#pragma unroll
        for (int j = 0; j < 16; ++j) {
            int i = tid + 256 * j;          // 0..4095
            int d = i >> 6, e = i & 63;
            Ws[e * 64 + (d ^ ((e & 7) << 2))] = W[i];
        }
    }
    // ---- phase 1: load Q/K tile, L2-normalize rows, write q/k outs, stage A^T ----
    {
        const int rr = tid >> 4;            // 16 rows per pass
        const int c4 = (tid & 15) << 2;     // 16 float4-chunks per row
#pragma unroll
        for (int p = 0; p < 4; ++p) {
            int r = p * 16 + rr;                          // row in tile
            int g = (bh * Nn + n0 + r) * Dd + c4;         // global elem index
            float4 q4 = *(const float4*)(Q + g);
            float4 k4 = *(const float4*)(Kp + g);
            float sq = q4.x*q4.x + q4.y*q4.y + q4.z*q4.z + q4.w*q4.w;
            float sk = k4.x*k4.x + k4.y*k4.y + k4.z*k4.z + k4.w*k4.w;
#pragma unroll
            for (int m = 1; m < 16; m <<= 1) {            // 16-lane row reduce
                sq += __shfl_xor(sq, m, 64);
                sk += __shfl_xor(sk, m, 64);
            }
            float iq = 1.0f / fmaxf(sqrtf(sq), 1e-12f);
            float ik = 1.0f / fmaxf(sqrtf(sk), 1e-12f);
            q4.x *= iq; q4.y *= iq; q4.z *= iq; q4.w *= iq;
            k4.x *= ik; k4.y *= ik; k4.z *= ik; k4.w *= ik;
            *(float4*)(out + O_Q + g) = q4;
            *(float4*)(out + O_K + g) = k4;
            A[aswz(c4 + 0, r)] = q4.x;  A[aswz(c4 + 0, r) + 64] = k4.x;
            A[aswz(c4 + 1, r)] = q4.y;  A[aswz(c4 + 1, r) + 64] = k4.y;
            A[aswz(c4 + 2, r)] = q4.z;  A[aswz(c4 + 2, r) + 64] = k4.z;
            A[aswz(c4 + 3, r)] = q4.w;  A[aswz(c4 + 3, r) + 64] = k4.w;
        }
    }
    __syncthreads();

    const int tc = tid & 15, tr = tid >> 4;
    const int c0 = tc << 2;                 // output cols (4)
    const int r0 = tr << 2;                 // output rows (4)

    // ---- GEMM1: S[n][c] = (c<32 ? Qn : Kn)[n][d] * Bs[d][c] ----
    float acc[4][4] = {};
    {
        const int aofs = (tc < 8) ? 0 : 64;   // escore cols use qn, rscore cols use kn
#pragma unroll 8
        for (int k = 0; k < 64; ++k) {
            float4 a4 = *(const float4*)(A + k * 128 + aofs + (r0 ^ ((k & 7) << 2)));
            float4 b4 = *(const float4*)(Bs + k * 64 + c0);
            const float av[4] = {a4.x, a4.y, a4.z, a4.w};
            const float bv[4] = {b4.x, b4.y, b4.z, b4.w};
#pragma unroll
            for (int i = 0; i < 4; ++i)
#pragma unroll
                for (int j = 0; j < 4; ++j)
                    acc[i][j] = fmaf(av[i], bv[j], acc[i][j]);
        }
    }
    // ---- write escore / rscore ----
    {
        float* sb = out + ((tc < 8) ? O_ES : O_RS);
        int ce = (tc & 7) << 2;
#pragma unroll
        for (int i = 0; i < 4; ++i) {
            int o = (bh * Nn + n0 + r0 + i) * 32 + ce;
            *(float4*)(sb + o) = make_float4(acc[i][0], acc[i][1], acc[i][2], acc[i][3]);
        }
    }
    __syncthreads();                         // all GEMM1 A-reads done
    // ---- St[c][n] over the A region (same swizzle) ----
#pragma unroll
    for (int j = 0; j < 4; ++j) {
        int c = c0 + j;
        *(float4*)(A + c * 128 + (r0 ^ ((c & 7) << 2))) =
            make_float4(acc[0][j], acc[1][j], acc[2][j], acc[3][j]);
    }
    __syncthreads();

    // ---- GEMM2: attn[n][d] = S[n][e] * W[d][e] (+b) * mask ----
    float acc2[4][4] = {};
#pragma unroll 8
    for (int k = 0; k < 64; ++k) {
        float4 a4 = *(const float4*)(A + k * 128 + (r0 ^ ((k & 7) << 2)));
        float4 b4 = *(const float4*)(Ws + k * 64 + (c0 ^ ((k & 7) << 2)));
        const float av[4] = {a4.x, a4.y, a4.z, a4.w};
        const float bv[4] = {b4.x, b4.y, b4.z, b4.w};
#pragma unroll
        for (int i = 0; i < 4; ++i)
#pragma unroll
            for (int j = 0; j < 4; ++j)
                acc2[i][j] = fmaf(av[i], bv[j], acc2[i][j]);
    }
    float4 b4 = *(const float4*)(bias + c0);
    const float bvv[4] = {b4.x, b4.y, b4.z, b4.w};
#pragma unroll
    for (int i = 0; i < 4; ++i) {
        int n = n0 + r0 + i;
        float mv = mask[bb * Nn + n];
        int o = (bh * Nn + n) * Dd + c0;
        float4 rr;
        rr.x = (acc2[i][0] + bvv[0]) * mv;
        rr.y = (acc2[i][1] + bvv[1]) * mv;
        rr.z = (acc2[i][2] + bvv[2]) * mv;
        rr.w = (acc2[i][3] + bvv[3]) * mv;
        *(float4*)(out + O_ATTN + o) = rr;
    }
}

extern "C" void kernel_launch(void* const* d_in, const int* in_sizes, int n_in,
                              void* d_out, int out_size, void* d_ws, size_t ws_size,
                              hipStream_t stream) {
    const float* Q    = (const float*)d_in[0];
    const float* Kp   = (const float*)d_in[1];
    const float* we   = (const float*)d_in[2];
    const float* wr   = (const float*)d_in[3];
    const float* mask = (const float*)d_in[4];
    const float* W    = (const float*)d_in[5];
    const float* bias = (const float*)d_in[6];
    const float* Lam  = (const float*)d_in[7];
    float* out = (float*)d_out;

    // passthrough outputs: we[0], wr[0] (first halves of we/wr), Lambda
    hipMemcpyAsync(out + O_WE,  we,  24576 * sizeof(float), hipMemcpyDeviceToDevice, stream);
    hipMemcpyAsync(out + O_WR,  wr,  24576 * sizeof(float), hipMemcpyDeviceToDevice, stream);
    hipMemcpyAsync(out + O_LAM, Lam,   384 * sizeof(float), hipMemcpyDeviceToDevice, stream);

    pca_fused<<<dim3(48 * 64), dim3(256), 0, stream>>>(Q, Kp, we, wr, mask, W, bias, out);
}

// Round 2
// 296.879 us; speedup vs baseline: 1.0332x; 1.0332x over previous
//
#include <hip/hip_runtime.h>

// PrimalCosAttention fused kernel (fp32, VALU GEMMs). R2:
//  - passthrough copies (we0/wr0/Lambda) folded into kernel (no SDMA nodes)
//  - 48 KiB LDS (W preloaded to regs, staged into Bs region after GEMM1)
//    -> 3 blocks/CU, 12 waves/CU
// B=4 H=12 N=4096 D=64 E=32. One block = one (b,h) x 64-row n-tile.

namespace {
constexpr int Hh = 12;
constexpr int Nn = 4096;
constexpr int Dd = 64;
// output offsets in floats
constexpr int O_ATTN = 0;
constexpr int O_ES   = 12582912;
constexpr int O_RS   = 18874368;
constexpr int O_WE   = 25165824;
constexpr int O_WR   = 25190400;
constexpr int O_Q    = 25214976;
constexpr int O_K    = 37797888;
constexpr int O_LAM  = 50380800;
}

// A-region swizzle: A is [d=64][128] (cols 0..63 = qn rows, 64..127 = kn rows).
__device__ __forceinline__ int aswz(int d, int r) {
    return d * 128 + (r ^ ((d & 7) << 2));
}

__global__ __launch_bounds__(256, 3)
void pca_fused(const float* __restrict__ Q, const float* __restrict__ Kp,
               const float* __restrict__ we, const float* __restrict__ wr,
               const float* __restrict__ mask, const float* __restrict__ W,
               const float* __restrict__ bias, const float* __restrict__ Lam,
               float* __restrict__ out)
{
    __shared__ float lds[12288];          // 48 KiB -> 3 blocks/CU
    float* A  = lds;                      // [64][128] swizzled qn|kn; reused as St
    float* Bs = lds + 8192;               // GEMM1: [d 64][64] we_h|wr_h; GEMM2: Ws

    const int tid = threadIdx.x;
    const int bh  = blockIdx.x >> 6;      // 0..47  (b*12+h)
    const int n0  = (blockIdx.x & 63) << 6;
    const int h   = bh % Hh;
    const int bb  = bh / Hh;

    // ---- passthrough outputs, float4, blocks 0..48 ----
    if (blockIdx.x < 49) {
        int i4 = blockIdx.x * 256 + tid;           // float4 index, 0..12383
        if (i4 < 6144) {
            ((float4*)(out + O_WE))[i4] = ((const float4*)we)[i4];
        } else if (i4 < 12288) {
            ((float4*)(out + O_WR))[i4 - 6144] = ((const float4*)wr)[i4 - 6144];
        } else if (i4 < 12384) {
            ((float4*)(out + O_LAM))[i4 - 12288] = ((const float4*)Lam)[i4 - 12288];
        }
    }

    // ---- preload W into registers (staged to LDS after GEMM1) ----
    float wreg[16];
#pragma unroll
    for (int j = 0; j < 16; ++j) wreg[j] = W[tid + 256 * j];

    // ---- stage Bs = [we_h | wr_h]  (row = d, col = e2) ----
    {
        const float* weh = we + h * 2048;
        const float* wrh = wr + h * 2048;
#pragma unroll
        for (int j = 0; j < 8; ++j) {
            int i = tid + 256 * j;          // 0..2047
            int d = i >> 5, e = i & 31;
            Bs[d * 64 + e]      = weh[i];
            Bs[d * 64 + 32 + e] = wrh[i];
        }
    }
    // ---- phase 1: load Q/K tile, L2-normalize rows, write q/k outs, stage A^T ----
    {
        const int rr = tid >> 4;
        const int c4 = (tid & 15) << 2;
#pragma unroll
        for (int p = 0; p < 4; ++p) {
            int r = p * 16 + rr;
            int g = (bh * Nn + n0 + r) * Dd + c4;
            float4 q4 = *(const float4*)(Q + g);
            float4 k4 = *(const float4*)(Kp + g);
            float sq = q4.x*q4.x + q4.y*q4.y + q4.z*q4.z + q4.w*q4.w;
            float sk = k4.x*k4.x + k4.y*k4.y + k4.z*k4.z + k4.w*k4.w;
#pragma unroll
            for (int m = 1; m < 16; m <<= 1) {
                sq += __shfl_xor(sq, m, 64);
                sk += __shfl_xor(sk, m, 64);
            }
            float iq = 1.0f / fmaxf(sqrtf(sq), 1e-12f);
            float ik = 1.0f / fmaxf(sqrtf(sk), 1e-12f);
            q4.x *= iq; q4.y *= iq; q4.z *= iq; q4.w *= iq;
            k4.x *= ik; k4.y *= ik; k4.z *= ik; k4.w *= ik;
            *(float4*)(out + O_Q + g) = q4;
            *(float4*)(out + O_K + g) = k4;
            A[aswz(c4 + 0, r)] = q4.x;  A[aswz(c4 + 0, r) + 64] = k4.x;
            A[aswz(c4 + 1, r)] = q4.y;  A[aswz(c4 + 1, r) + 64] = k4.y;
            A[aswz(c4 + 2, r)] = q4.z;  A[aswz(c4 + 2, r) + 64] = k4.z;
            A[aswz(c4 + 3, r)] = q4.w;  A[aswz(c4 + 3, r) + 64] = k4.w;
        }
    }
    __syncthreads();

    const int tc = tid & 15, tr = tid >> 4;
    const int c0 = tc << 2;
    const int r0 = tr << 2;

    // ---- GEMM1: S[n][c] = (c<32 ? Qn : Kn)[n][d] * Bs[d][c] ----
    float acc[4][4] = {};
    {
        const int aofs = (tc < 8) ? 0 : 64;
#pragma unroll 8
        for (int k = 0; k < 64; ++k) {
            float4 a4 = *(const float4*)(A + k * 128 + aofs + (r0 ^ ((k & 7) << 2)));
            float4 b4 = *(const float4*)(Bs + k * 64 + c0);
            const float av[4] = {a4.x, a4.y, a4.z, a4.w};
            const float bv[4] = {b4.x, b4.y, b4.z, b4.w};
#pragma unroll
            for (int i = 0; i < 4; ++i)
#pragma unroll
                for (int j = 0; j < 4; ++j)
                    acc[i][j] = fmaf(av[i], bv[j], acc[i][j]);
        }
    }
    // ---- write escore / rscore ----
    {
        float* sb = out + ((tc < 8) ? O_ES : O_RS);
        int ce = (tc & 7) << 2;
#pragma unroll
        for (int i = 0; i < 4; ++i) {
            int o = (bh * Nn + n0 + r0 + i) * 32 + ce;
            *(float4*)(sb + o) = make_float4(acc[i][0], acc[i][1], acc[i][2], acc[i][3]);
        }
    }
    __syncthreads();                         // all GEMM1 A/Bs reads done
    // ---- St[c][n] into A region; Ws (from regs) into Bs region ----
#pragma unroll
    for (int j = 0; j < 4; ++j) {
        int c = c0 + j;
        *(float4*)(A + c * 128 + (r0 ^ ((c & 7) << 2))) =
            make_float4(acc[0][j], acc[1][j], acc[2][j], acc[3][j]);
    }
#pragma unroll
    for (int j = 0; j < 16; ++j) {
        int i = tid + 256 * j;              // W flat index: d = i>>6, e = i&63
        int d = i >> 6, e = i & 63;
        Bs[e * 64 + (d ^ ((e & 7) << 2))] = wreg[j];
    }
    __syncthreads();

    // ---- GEMM2: attn[n][d] = S[n][e] * W[d][e] (+b) * mask ----
    float acc2[4][4] = {};
#pragma unroll 8
    for (int k = 0; k < 64; ++k) {
        float4 a4 = *(const float4*)(A + k * 128 + (r0 ^ ((k & 7) << 2)));
        float4 b4 = *(const float4*)(Bs + k * 64 + (c0 ^ ((k & 7) << 2)));
        const float av[4] = {a4.x, a4.y, a4.z, a4.w};
        const float bv[4] = {b4.x, b4.y, b4.z, b4.w};
#pragma unroll
        for (int i = 0; i < 4; ++i)
#pragma unroll
            for (int j = 0; j < 4; ++j)
                acc2[i][j] = fmaf(av[i], bv[j], acc2[i][j]);
    }
    float4 b4 = *(const float4*)(bias + c0);
    const float bvv[4] = {b4.x, b4.y, b4.z, b4.w};
#pragma unroll
    for (int i = 0; i < 4; ++i) {
        int n = n0 + r0 + i;
        float mv = mask[bb * Nn + n];
        int o = (bh * Nn + n) * Dd + c0;
        float4 rr;
        rr.x = (acc2[i][0] + bvv[0]) * mv;
        rr.y = (acc2[i][1] + bvv[1]) * mv;
        rr.z = (acc2[i][2] + bvv[2]) * mv;
        rr.w = (acc2[i][3] + bvv[3]) * mv;
        *(float4*)(out + O_ATTN + o) = rr;
    }
}

extern "C" void kernel_launch(void* const* d_in, const int* in_sizes, int n_in,
                              void* d_out, int out_size, void* d_ws, size_t ws_size,
                              hipStream_t stream) {
    const float* Q    = (const float*)d_in[0];
    const float* Kp   = (const float*)d_in[1];
    const float* we   = (const float*)d_in[2];
    const float* wr   = (const float*)d_in[3];
    const float* mask = (const float*)d_in[4];
    const float* W    = (const float*)d_in[5];
    const float* bias = (const float*)d_in[6];
    const float* Lam  = (const float*)d_in[7];
    float* out = (float*)d_out;

    pca_fused<<<dim3(48 * 64), dim3(256), 0, stream>>>(Q, Kp, we, wr, mask, W, bias, Lam, out);
}